// Round 1
// baseline (266.183 us; speedup 1.0000x reference)
//
#include <hip/hip_runtime.h>
#include <stdint.h>

#define TW_N 2047
#define BATCH 8
#define T_LEN 65536
#define NCH 64
#define HID 512
#define NWIN (BATCH * TW_N) /* 16376 */

typedef unsigned short ushortT;

// ---------- bf16 pack helpers ----------
__device__ __forceinline__ ushortT f2b(float f) {
  union { float f; uint32_t i; } v; v.f = f;
  uint32_t r = v.i + 0x7fffu + ((v.i >> 16) & 1u);
  return (ushortT)(r >> 16);
}
__device__ __forceinline__ uint32_t pk2(float lo, float hi) {
  return (uint32_t)f2b(lo) | ((uint32_t)f2b(hi) << 16);
}

// ---------- async global->LDS, 16B per lane (dest must be linear in lane order) ----------
__device__ __forceinline__ void gload_lds16(const void* g, void* l) {
  __builtin_amdgcn_global_load_lds(
      (const __attribute__((address_space(1))) uint32_t*)g,
      (__attribute__((address_space(3))) uint32_t*)l, 16, 0, 0);
}

// ---------- compile-time DFT twiddles: cos/sin(2*pi*m/64) ----------
constexpr float CQ[17] = {
  1.0f, 0.9951847267f, 0.9807852804f, 0.9569403357f, 0.9238795325f,
  0.8819212643f, 0.8314696123f, 0.7730104534f, 0.7071067812f, 0.6343932842f,
  0.5555702330f, 0.4713967368f, 0.3826834324f, 0.2902846773f, 0.1950903220f,
  0.0980171403f, 0.0f };
constexpr float cos64(int m) {
  m &= 63;
  return (m <= 16) ? CQ[m] : (m < 32) ? -CQ[32 - m] : (m < 48) ? -CQ[m - 32] : CQ[64 - m];
}
constexpr float sin64(int m) { return cos64(m - 16); }
struct TwTab { float c[24][32]; float s[24][32]; };
constexpr TwTab make_tab() {
  TwTab t{};
  for (int i = 0; i < 24; ++i)
    for (int j = 0; j < 32; ++j) {
      int m = ((i + 1) * j) & 63;
      t.c[i][j] = cos64(m);
      t.s[i][j] = sin64(m);
    }
  return t;
}
constexpr TwTab TT = make_tab();

// bf16-packed mix_w, written once per launch by prep_kernel
__device__ ushortT Bpack[HID * HID];   // 512 KB device-global

// ---------- K0: marker rows + mix_w fp32->bf16 pre-pack ----------
__global__ __launch_bounds__(256) void prep_kernel(
    const float* __restrict__ marker, const float* __restrict__ Bw,
    float* __restrict__ out)
{
  const int gid = blockIdx.x * 256 + threadIdx.x;
  if (blockIdx.x < 16) {
    // 4096 threads: out[b,0,:] = marker
    out[(size_t)(gid >> 9) * (2048 * 512) + (gid & 511)] = marker[gid & 511];
  } else {
    // 32768 threads * 8 elems = 262144 = 512*512
    const int i = (gid - 4096) * 8;
    const float4 f0 = *(const float4*)(Bw + i);
    const float4 f1 = *(const float4*)(Bw + i + 4);
    uint4 u;
    u.x = pk2(f0.x, f0.y); u.y = pk2(f0.z, f0.w);
    u.z = pk2(f1.x, f1.y); u.w = pk2(f1.z, f1.w);
    *(uint4*)(Bpack + i) = u;
  }
}

// ---------- K1: LDS-staged windows -> 7 feats -> per-channel embed -> flat bf16 ----------
// block = 512 threads (8 waves), one tile of 8 consecutive windows of one batch.
// Stages 288 rows (64 + 7*32) once: 72 KB LDS, 151 MB total vs 268 MB un-staged.
#define WPB 8
#define SROWS 288   /* 64 + (WPB-1)*32 */

__global__ __launch_bounds__(512) void feat_embed_kernel(
    const float* __restrict__ sig, const float* __restrict__ chw,
    const float* __restrict__ chb, ushortT* __restrict__ flatB)
{
  __shared__ float xs[SROWS * NCH];   // 73728 B -> 2 blocks/CU
  const int tid = threadIdx.x;
  const int tile = blockIdx.x;        // 0..255
  const int b = blockIdx.y;           // 0..7
  const int t0 = tile * (WPB * 32);   // first signal row of tile

  // ---- stage: 288 rows x 64 ch, 16 B/lane DMA, linear LDS (lane order == idx) ----
  const float* sgb = sig + (size_t)b * T_LEN * NCH;
#pragma unroll
  for (int k = 0; k < 9; ++k) {
    const int idx = tid + k * 512;        // 0..4607 float4 slots
    int row = t0 + (idx >> 4);
    row = row < T_LEN ? row : T_LEN - 1;  // tail tile: staged-but-unused rows clamp
    gload_lds16(sgb + (size_t)row * NCH + (idx & 15) * 4, (char*)xs + (size_t)idx * 16);
  }
  __syncthreads();   // drains vmcnt(0): DMA complete

  // ---- per-wave window, lane = channel; radix-2 butterfly folded into LDS reads ----
  const int wv = tid >> 6;
  const int c = tid & 63;
  int wl = tile * WPB + wv;
  wl = wl < TW_N ? wl : TW_N - 1;         // last tile: wave 7 duplicates wave 6 (benign)
  const int lv = wl - tile * WPB;         // local window slot actually computed
  const float* base = xs + lv * (32 * NCH) + c;   // stride-4B across lanes: conflict-free

  float e[32], o[32];
  float sum = 0.f, sumsq = 0.f;
#pragma unroll
  for (int t = 0; t < 32; ++t) {
    const float a = base[t * 64];
    const float d = base[(t + 32) * 64];
    e[t] = a + d; o[t] = a - d;
    sum += e[t];
    sumsq = fmaf(a, a, fmaf(d, d, sumsq));
  }

  // X_k = sum_{t<32} (k even ? e : o)[t] * w^{kt},  k = 1..24
  float b1 = 0.f, b2 = 0.f, b3 = 0.f, b4 = 0.f;
#pragma unroll
  for (int i = 0; i < 24; ++i) {
    const int k = i + 1;
    float re = 0.f, im = 0.f;
#pragma unroll
    for (int t = 0; t < 32; ++t) {
      const float v = (k & 1) ? o[t] : e[t];
      re = fmaf(v, TT.c[i][t], re);
      im = fmaf(v, TT.s[i][t], im);
    }
    const float mag = sqrtf(fmaf(re, re, im * im));
    if (k == 1) b1 += mag;
    else if (k < 4) b2 += mag;
    else if (k < 8) b3 += mag;
    else b4 += mag;
  }

  const float mean = sum * (1.f / 64.f);
  const float var = (sumsq - sum * sum * (1.f / 64.f)) * (1.f / 63.f);
  const float sd = sqrtf(fmaxf(var, 0.f));

  float feats[7];
  feats[0] = 0.f;               // band (0.5,4): no bins at 4 Hz resolution
  feats[1] = b1;
  feats[2] = b2 * 0.5f;
  feats[3] = b3 * 0.25f;
  feats[4] = b4 * (1.f / 17.f);
  feats[5] = mean;
  feats[6] = sd;

  const float* wr = chw + c * 56;
  float emb[8];
#pragma unroll
  for (int p = 0; p < 8; ++p) emb[p] = chb[c * 8 + p];
#pragma unroll
  for (int f = 1; f < 7; ++f) {
    const float fv = feats[f];
#pragma unroll
    for (int p = 0; p < 8; ++p) emb[p] = fmaf(fv, wr[f * 8 + p], emb[p]);
  }

  uint32_t pka[4];
#pragma unroll
  for (int q = 0; q < 4; ++q) pka[q] = pk2(emb[2 * q], emb[2 * q + 1]);
  const int w = b * TW_N + wl;
  *(uint4*)(flatB + (size_t)w * HID + c * 8) = make_uint4(pka[0], pka[1], pka[2], pka[3]);
}

// ---------- K2: z = flat @ mix_w^T + PE, m97-style global_load_lds GEMM ----------
typedef __attribute__((ext_vector_type(8))) short short8;
typedef __attribute__((ext_vector_type(4))) float f32x4;

__global__ __launch_bounds__(256) void mix_gemm_kernel(
    const ushortT* __restrict__ A,    // flatB [16376][512] bf16 (ws)
    float* __restrict__ out)
{
  __shared__ ushortT As[2][128 * 32];  // double-buffered, 8 KB per buf
  __shared__ ushortT Bs[2][128 * 32];

  const int tid = threadIdx.x;
  const int lane = tid & 63;
  const int wv = tid >> 6;
  const int wm = wv >> 1, wn = wv & 1;
  const int fr = lane & 15;
  const int fq = lane >> 4;

  const int n0 = blockIdx.x * 128;   // 4 col-blocks
  const int m0 = blockIdx.y * 128;   // 128 row-blocks

  const int srow = tid >> 2;         // 64 rows per DMA pass
  const int sko = (tid & 3) * 8;     // k-offset in elements

  f32x4 acc[4][4];
#pragma unroll
  for (int i = 0; i < 4; ++i)
#pragma unroll
    for (int j = 0; j < 4; ++j) acc[i][j] = (f32x4){0.f, 0.f, 0.f, 0.f};

  int am0 = m0 + srow;       am0 = am0 < NWIN ? am0 : NWIN - 1;
  int am1 = m0 + 64 + srow;  am1 = am1 < NWIN ? am1 : NWIN - 1;
  const ushortT* ga0 = A + (size_t)am0 * HID + sko;
  const ushortT* ga1 = A + (size_t)am1 * HID + sko;
  const ushortT* gb0 = Bpack + (size_t)(n0 + srow) * HID + sko;
  const ushortT* gb1 = Bpack + (size_t)(n0 + 64 + srow) * HID + sko;

  // LDS dest byte offsets are tid*16 (+4096 for second 64 rows): linear in lane order.
#define STAGE(buf, kt) do {                                                    \
    const int ko_ = (kt) * 32;                                                 \
    gload_lds16(ga0 + ko_, (char*)&As[buf][0] + tid * 16);                     \
    gload_lds16(ga1 + ko_, (char*)&As[buf][0] + 4096 + tid * 16);              \
    gload_lds16(gb0 + ko_, (char*)&Bs[buf][0] + tid * 16);                     \
    gload_lds16(gb1 + ko_, (char*)&Bs[buf][0] + 4096 + tid * 16);              \
  } while (0)

  STAGE(0, 0);

  for (int kt = 0; kt < 16; ++kt) {
    const int cur = kt & 1;
    if (kt < 15) {
      STAGE(cur ^ 1, kt + 1);
      // wait only for current buffer's 4 DMAs; next tile's 4 stay in flight
      asm volatile("s_waitcnt vmcnt(4)\n\ts_barrier" ::: "memory");
    } else {
      asm volatile("s_waitcnt vmcnt(0)\n\ts_barrier" ::: "memory");
    }

    short8 af[4], bf[4];
#pragma unroll
    for (int mt = 0; mt < 4; ++mt)
      af[mt] = *(const short8*)&As[cur][(wm * 64 + mt * 16 + fr) * 32 + fq * 8];
#pragma unroll
    for (int nt = 0; nt < 4; ++nt)
      bf[nt] = *(const short8*)&Bs[cur][(wn * 64 + nt * 16 + fr) * 32 + fq * 8];
#pragma unroll
    for (int mt = 0; mt < 4; ++mt)
#pragma unroll
      for (int nt = 0; nt < 4; ++nt)
        acc[mt][nt] = __builtin_amdgcn_mfma_f32_16x16x32_bf16(af[mt], bf[nt], acc[mt][nt], 0, 0, 0);

    // all waves done reading buf 'cur' before next iter DMAs into it
    asm volatile("s_barrier" ::: "memory");
  }
#undef STAGE

  // epilogue (fp32 out): C/D layout col(n)=lane&15, row(m)=(lane>>4)*4+reg.
#pragma unroll
  for (int nt = 0; nt < 4; ++nt) {
    const int ng = n0 + wn * 64 + nt * 16 + fr;
    const float dv = __expf(-0.03597789208f * (float)(ng >> 1));
    const bool odd = (ng & 1);
#pragma unroll
    for (int mt = 0; mt < 4; ++mt) {
#pragma unroll
      for (int r = 0; r < 4; ++r) {
        const int mg = m0 + wm * 64 + mt * 16 + fq * 4 + r;
        if (mg < NWIN) {
          const int bb = mg / TW_N;
          const int tw = mg - bb * TW_N;
          const float ang = (float)tw * dv;
          const float pev = odd ? __cosf(ang) : __sinf(ang);
          out[((size_t)(bb * 2048 + 1 + tw)) * HID + ng] = acc[mt][nt][r] + pev;
        }
      }
    }
  }
}

extern "C" void kernel_launch(void* const* d_in, const int* in_sizes, int n_in,
                              void* d_out, int out_size, void* d_ws, size_t ws_size,
                              hipStream_t stream)
{
  const float* sig = (const float*)d_in[0];
  const float* chw = (const float*)d_in[1];
  const float* chb = (const float*)d_in[2];
  const float* mxw = (const float*)d_in[3];
  const float* mkr = (const float*)d_in[4];
  float* out = (float*)d_out;

  ushortT* flatB = (ushortT*)d_ws;   // 16,769,024 B — only ws use

  hipLaunchKernelGGL(prep_kernel, dim3(144), dim3(256), 0, stream, mkr, mxw, out);
  hipLaunchKernelGGL(feat_embed_kernel, dim3(256, 8), dim3(512), 0, stream, sig, chw, chb, flatB);
  hipLaunchKernelGGL(mix_gemm_kernel, dim3(4, 128), dim3(256), 0, stream, flatB, out);
}

// Round 2
// 249.753 us; speedup vs baseline: 1.0658x; 1.0658x over previous
//
#include <hip/hip_runtime.h>
#include <stdint.h>

#define TW_N 2047
#define BATCH 8
#define T_LEN 65536
#define NCH 64
#define HID 512
#define NWIN (BATCH * TW_N) /* 16376 */

typedef unsigned short ushortT;

// ---------- bf16 pack helpers ----------
__device__ __forceinline__ ushortT f2b(float f) {
  union { float f; uint32_t i; } v; v.f = f;
  uint32_t r = v.i + 0x7fffu + ((v.i >> 16) & 1u);
  return (ushortT)(r >> 16);
}
__device__ __forceinline__ uint32_t pk2(float lo, float hi) {
  return (uint32_t)f2b(lo) | ((uint32_t)f2b(hi) << 16);
}

// ---------- async global->LDS, 16B per lane (dest linear in lane order) ----------
__device__ __forceinline__ void gload_lds16(const void* g, void* l) {
  __builtin_amdgcn_global_load_lds(
      (const __attribute__((address_space(1))) uint32_t*)g,
      (__attribute__((address_space(3))) uint32_t*)l, 16, 0, 0);
}

// ---------- compile-time DFT twiddles: cos/sin(2*pi*m/64) ----------
constexpr float CQ[17] = {
  1.0f, 0.9951847267f, 0.9807852804f, 0.9569403357f, 0.9238795325f,
  0.8819212643f, 0.8314696123f, 0.7730104534f, 0.7071067812f, 0.6343932842f,
  0.5555702330f, 0.4713967368f, 0.3826834324f, 0.2902846773f, 0.1950903220f,
  0.0980171403f, 0.0f };
constexpr float cos64(int m) {
  m &= 63;
  return (m <= 16) ? CQ[m] : (m < 32) ? -CQ[32 - m] : (m < 48) ? -CQ[m - 32] : CQ[64 - m];
}
constexpr float sin64(int m) { return cos64(m - 16); }
struct TwTab { float c[24][32]; float s[24][32]; };
constexpr TwTab make_tab() {
  TwTab t{};
  for (int i = 0; i < 24; ++i)
    for (int j = 0; j < 32; ++j) {
      int m = ((i + 1) * j) & 63;
      t.c[i][j] = cos64(m);
      t.s[i][j] = sin64(m);
    }
  return t;
}
constexpr TwTab TT = make_tab();

// bf16-packed mix_w, written once per launch by prep_kernel
__device__ ushortT Bpack[HID * HID];   // 512 KB device-global

// ---------- K0: marker rows + mix_w fp32->bf16 pre-pack ----------
__global__ __launch_bounds__(256) void prep_kernel(
    const float* __restrict__ marker, const float* __restrict__ Bw,
    float* __restrict__ out)
{
  const int gid = blockIdx.x * 256 + threadIdx.x;
  if (blockIdx.x < 16) {
    out[(size_t)(gid >> 9) * (2048 * 512) + (gid & 511)] = marker[gid & 511];
  } else {
    const int i = (gid - 4096) * 8;
    const float4 f0 = *(const float4*)(Bw + i);
    const float4 f1 = *(const float4*)(Bw + i + 4);
    uint4 u;
    u.x = pk2(f0.x, f0.y); u.y = pk2(f0.z, f0.w);
    u.z = pk2(f1.x, f1.y); u.w = pk2(f1.z, f1.w);
    *(uint4*)(Bpack + i) = u;
  }
}

// ---------- K1: barrier-free streaming feature kernel ----------
// One wave = 8 consecutive windows of one batch, lane = channel.
// Halves A,Bh in registers; R prefetches the next 32 rows UNDER the DFT.
// No LDS, no barriers; 2048 waves, all co-resident.
__global__ __launch_bounds__(256) void feat_embed_kernel(
    const float* __restrict__ sig, const float* __restrict__ chw,
    const float* __restrict__ chb, ushortT* __restrict__ flatB)
{
  const int tid = threadIdx.x;
  const int c = tid & 63;
  const int gw = blockIdx.x * 4 + (tid >> 6);   // 0..2047
  const int b = gw >> 8;                        // batch
  const int run = gw & 255;                     // run within batch
  const int tw0 = run * 8;
  const int nw = (tw0 + 8 <= TW_N) ? 8 : (TW_N - tw0);   // 8, or 7 for run 255
  const float* sg = sig + ((size_t)b * T_LEN + (size_t)tw0 * 32) * NCH + c;
  const float* wr = chw + c * 56;

  float A[32], Bh[32], O[32], R[32];
#pragma unroll
  for (int t = 0; t < 32; ++t) A[t] = sg[t * 64];
#pragma unroll
  for (int t = 0; t < 32; ++t) Bh[t] = sg[(t + 32) * 64];

#pragma unroll 1
  for (int l = 0; l < nw; ++l) {
    // prefetch half h_{l+2} (clamped at batch end; garbage rows never used)
    {
      int hrow = (tw0 + l + 2) * 32;
      hrow = hrow < (T_LEN - 32) ? hrow : (T_LEN - 32);
      const float* pn = sig + ((size_t)b * T_LEN + hrow) * NCH + c;
#pragma unroll
      for (int t = 0; t < 32; ++t) R[t] = pn[t * 64];
    }

    // radix-2 butterfly: A <- e = a+d, O <- o = a-d ; sumsq = sum(e^2+o^2) = 2*sum(x^2)
    float sum = 0.f, sumsq = 0.f;
#pragma unroll
    for (int t = 0; t < 32; ++t) {
      O[t] = A[t] - Bh[t];
      A[t] = A[t] + Bh[t];
      sum += A[t];
      sumsq = fmaf(A[t], A[t], fmaf(O[t], O[t], sumsq));
    }

    // X_k = sum_{t<32} (k odd ? O : A)[t] * w^{kt},  k = 1..24 (fully unrolled, literal twiddles)
    float b1 = 0.f, b2 = 0.f, b3 = 0.f, b4 = 0.f;
#pragma unroll
    for (int i = 0; i < 24; ++i) {
      const int k = i + 1;
      float re = 0.f, im = 0.f;
#pragma unroll
      for (int t = 0; t < 32; ++t) {
        const float v = (k & 1) ? O[t] : A[t];
        re = fmaf(v, TT.c[i][t], re);
        im = fmaf(v, TT.s[i][t], im);
      }
      const float mag = __builtin_amdgcn_sqrtf(fmaf(re, re, im * im));
      if (k == 1) b1 += mag;
      else if (k < 4) b2 += mag;
      else if (k < 8) b3 += mag;
      else b4 += mag;
    }

    const float mean = sum * (1.f / 64.f);
    const float var = (sumsq * 0.5f - sum * sum * (1.f / 64.f)) * (1.f / 63.f);
    const float sd = __builtin_amdgcn_sqrtf(fmaxf(var, 0.f));

    const float f1 = b1, f2 = b2 * 0.5f, f3 = b3 * 0.25f, f4 = b4 * (1.f / 17.f);
    float emb[8];
#pragma unroll
    for (int p = 0; p < 8; ++p) emb[p] = chb[c * 8 + p];
#pragma unroll
    for (int p = 0; p < 8; ++p) {
      float e = emb[p];
      e = fmaf(f1, wr[8 + p], e);
      e = fmaf(f2, wr[16 + p], e);
      e = fmaf(f3, wr[24 + p], e);
      e = fmaf(f4, wr[32 + p], e);
      e = fmaf(mean, wr[40 + p], e);
      e = fmaf(sd, wr[48 + p], e);
      emb[p] = e;
    }

    uint32_t pka[4];
#pragma unroll
    for (int q = 0; q < 4; ++q) pka[q] = pk2(emb[2 * q], emb[2 * q + 1]);
    const int w = b * TW_N + tw0 + l;
    *(uint4*)(flatB + (size_t)w * HID + c * 8) = make_uint4(pka[0], pka[1], pka[2], pka[3]);

    // rotate halves: A <- h_{l+1}, Bh <- h_{l+2}
#pragma unroll
    for (int t = 0; t < 32; ++t) { A[t] = Bh[t]; Bh[t] = R[t]; }
  }
}

// ---------- K2: z = flat @ mix_w^T + PE, depth-2 pipelined MFMA GEMM ----------
typedef __attribute__((ext_vector_type(8))) short short8;
typedef __attribute__((ext_vector_type(4))) float f32x4;

__global__ __launch_bounds__(256) void mix_gemm_kernel(
    const ushortT* __restrict__ A,    // flatB [16376][512] bf16 (ws)
    float* __restrict__ out)
{
  __shared__ ushortT As[3][128 * 32];  // 3-buffer ring, 8 KB each side
  __shared__ ushortT Bs[3][128 * 32];

  const int tid = threadIdx.x;
  const int lane = tid & 63;
  const int wv = tid >> 6;
  const int wm = wv >> 1, wn = wv & 1;
  const int fr = lane & 15;
  const int fq = lane >> 4;

  const int n0 = blockIdx.x * 128;   // 4 col-blocks
  const int m0 = blockIdx.y * 128;   // 128 row-blocks

  const int srow = tid >> 2;         // 64 rows per DMA pass
  const int sko = (tid & 3) * 8;     // k-offset in elements

  f32x4 acc[4][4];
#pragma unroll
  for (int i = 0; i < 4; ++i)
#pragma unroll
    for (int j = 0; j < 4; ++j) acc[i][j] = (f32x4){0.f, 0.f, 0.f, 0.f};

  int am0 = m0 + srow;       am0 = am0 < NWIN ? am0 : NWIN - 1;
  int am1 = m0 + 64 + srow;  am1 = am1 < NWIN ? am1 : NWIN - 1;
  const ushortT* ga0 = A + (size_t)am0 * HID + sko;
  const ushortT* ga1 = A + (size_t)am1 * HID + sko;
  const ushortT* gb0 = Bpack + (size_t)(n0 + srow) * HID + sko;
  const ushortT* gb1 = Bpack + (size_t)(n0 + 64 + srow) * HID + sko;

#define STAGE(buf, kt) do {                                                    \
    const int ko_ = (kt) * 32;                                                 \
    gload_lds16(ga0 + ko_, (char*)&As[buf][0] + tid * 16);                     \
    gload_lds16(ga1 + ko_, (char*)&As[buf][0] + 4096 + tid * 16);              \
    gload_lds16(gb0 + ko_, (char*)&Bs[buf][0] + tid * 16);                     \
    gload_lds16(gb1 + ko_, (char*)&Bs[buf][0] + 4096 + tid * 16);              \
  } while (0)

  STAGE(0, 0);
  STAGE(1, 1);

  int c0 = 0, c1 = 1, c2 = 2;   // ring: c0 = current, c2 = stage target
  for (int kt = 0; kt < 16; ++kt) {
    if (kt < 14) {
      STAGE(c2, kt + 2);
      // 8 DMAs (stages kt+1, kt+2) stay in flight; kt's 4 are complete
      asm volatile("s_waitcnt vmcnt(8)\n\ts_barrier" ::: "memory");
    } else if (kt == 14) {
      asm volatile("s_waitcnt vmcnt(4)\n\ts_barrier" ::: "memory");
    } else {
      asm volatile("s_waitcnt vmcnt(0)\n\ts_barrier" ::: "memory");
    }

    short8 af[4], bf[4];
#pragma unroll
    for (int mt = 0; mt < 4; ++mt)
      af[mt] = *(const short8*)&As[c0][(wm * 64 + mt * 16 + fr) * 32 + fq * 8];
#pragma unroll
    for (int nt = 0; nt < 4; ++nt)
      bf[nt] = *(const short8*)&Bs[c0][(wn * 64 + nt * 16 + fr) * 32 + fq * 8];
#pragma unroll
    for (int mt = 0; mt < 4; ++mt)
#pragma unroll
      for (int nt = 0; nt < 4; ++nt)
        acc[mt][nt] = __builtin_amdgcn_mfma_f32_16x16x32_bf16(af[mt], bf[nt], acc[mt][nt], 0, 0, 0);

    // all waves done reading buf c0 before anyone DMAs into it next iter
    asm volatile("s_barrier" ::: "memory");
    const int tmp = c0; c0 = c1; c1 = c2; c2 = tmp;
  }
#undef STAGE

  // epilogue (fp32 out): C/D layout col(n)=lane&15, row(m)=(lane>>4)*4+reg.
#pragma unroll
  for (int nt = 0; nt < 4; ++nt) {
    const int ng = n0 + wn * 64 + nt * 16 + fr;
    const float dv = __expf(-0.03597789208f * (float)(ng >> 1));
    const bool odd = (ng & 1);
#pragma unroll
    for (int mt = 0; mt < 4; ++mt) {
#pragma unroll
      for (int r = 0; r < 4; ++r) {
        const int mg = m0 + wm * 64 + mt * 16 + fq * 4 + r;
        if (mg < NWIN) {
          const int bb = mg / TW_N;
          const int tw = mg - bb * TW_N;
          const float ang = (float)tw * dv;
          const float pev = odd ? __cosf(ang) : __sinf(ang);
          out[((size_t)(bb * 2048 + 1 + tw)) * HID + ng] = acc[mt][nt][r] + pev;
        }
      }
    }
  }
}

extern "C" void kernel_launch(void* const* d_in, const int* in_sizes, int n_in,
                              void* d_out, int out_size, void* d_ws, size_t ws_size,
                              hipStream_t stream)
{
  const float* sig = (const float*)d_in[0];
  const float* chw = (const float*)d_in[1];
  const float* chb = (const float*)d_in[2];
  const float* mxw = (const float*)d_in[3];
  const float* mkr = (const float*)d_in[4];
  float* out = (float*)d_out;

  ushortT* flatB = (ushortT*)d_ws;

  hipLaunchKernelGGL(prep_kernel, dim3(144), dim3(256), 0, stream, mkr, mxw, out);
  hipLaunchKernelGGL(feat_embed_kernel, dim3(512), dim3(256), 0, stream, sig, chw, chb, flatB);
  hipLaunchKernelGGL(mix_gemm_kernel, dim3(4, 128), dim3(256), 0, stream, flatB, out);
}